// Round 8
// baseline (476.280 us; speedup 1.0000x reference)
//
#include <hip/hip_runtime.h>

// BNN conv3d forward: x (8,32,16,160,160) f32, w (32,32,1,3,3) f32
// out[n,o,d,h,w] = sum_i sum_{kh,kw} x[n,i,d,h+kh-1,w+kw-1] * we[o,i,kh,kw]
// we = (mean|w| over taps) * sign(w).  Implicit GEMM, mfma_f32_16x16x32_f16.
//
// Round-8: R6 ring with the self-draining-prefetch bug fixed. All prior
// rounds guarded staging loads per-lane (`ok ? load : 0`) -> v_cndmask needs
// the load RESULT -> s_waitcnt inside the issue phase -> nothing ever stayed
// in flight (VGPR_Count 48-52 proved it). Now the guard is a block-uniform
// branch on the stage-unit index: interior units issue unconditional float4
// loads whose first consumer (PACK) is 2+ barriers later. Steady state keeps
// ~2 stage-units (80 KB/block) of reads outstanding across COMPUTE.
// Geometry: full-row TH-style tiles (write-exact), chunk = 10 output rows,
// grid 2048, 320 thr (5 waves), LDS ring 6 x 162 x 32 f16 = 62 KB.

typedef _Float16 half8 __attribute__((ext_vector_type(8)));
typedef float    floatx4 __attribute__((ext_vector_type(4)));

#define DHW  409600   // 16*160*160
#define HW   25600    // 160*160
#define ROWB (162*32) // halfs per ring row-slot

__device__ __forceinline__ int lds_half_idx(int slot, int w1, int kg) {
    // round-5-verified swizzle: 64B-cell swap + 16B sub-block XOR
    const int w1x = w1 ^ ((w1 >> 2) & 1);
    const int skg = kg ^ (((w1 >> 1) ^ (w1 >> 3)) & 3);
    return slot * ROWB + w1x * 32 + skg * 8;
}

__device__ __forceinline__ void barrier_raw() {
    // LDS-visibility barrier that does NOT drain vmcnt (loads stay in flight)
    __builtin_amdgcn_sched_barrier(0);
    asm volatile("s_waitcnt lgkmcnt(0)" ::: "memory");
    __builtin_amdgcn_s_barrier();
    __builtin_amdgcn_sched_barrier(0);
}

// ---- kernel 1: effective-weight fragments -> ws (18 KB) -------------------
// ws[((t*2+p)*64 + l)*8 + j] = we[o=p*16+(l&15)][i=(l>>4)*8+j][t]
__global__ void bnn_wprep_kernel(const float* __restrict__ w,
                                 _Float16* __restrict__ ws) {
    const int tid = threadIdx.x;
    #pragma unroll
    for (int p4 = 0; p4 < 4; ++p4) {
        const int oi = tid * 4 + p4;
        const int o  = oi >> 5;
        const int i  = oi & 31;
        const float* wp = w + oi * 9;
        float s = 0.f;
        #pragma unroll
        for (int t = 0; t < 9; ++t) s += fabsf(wp[t]);
        s *= (1.f / 9.f);
        const int l = ((i >> 3) << 4) | (o & 15);
        const int p = o >> 4;
        const int j = i & 7;
        #pragma unroll
        for (int t = 0; t < 9; ++t) {
            const float v  = wp[t];
            const float sg = (v > 0.f) ? 1.f : ((v < 0.f) ? -1.f : 0.f);
            ws[((t * 2 + p) * 64 + l) * 8 + j] = (_Float16)(s * sg);
        }
    }
}

struct SR { floatx4 v[8]; };   // one stage-unit's per-thread data (32 VGPR)

// ---- kernel 2: the conv ---------------------------------------------------
__global__ __launch_bounds__(320, 3) void bnn_conv3d_ring(
        const float* __restrict__ x, const _Float16* __restrict__ ws,
        float* __restrict__ out) {
    __shared__ __align__(16) _Float16 ldsh[6 * ROWB];   // 62208 B ring

    const int tid  = threadIdx.x;
    const int lane = tid & 63;

    const int bid = blockIdx.x;        // 2048 = 8n * 16d * 16 h-chunks
    const int chk = bid & 15;
    const int nd  = bid >> 4;
    const int d   = nd & 15;
    const int n   = nd >> 4;
    const int h0  = chk * 10;          // block owns output rows h0..h0+9

    // staging coords: item = (rr:2, kg:4, wq:40) = 320 = blockDim
    const int wq   = tid % 40;
    const int kg_s = (tid / 40) & 3;
    const int rr   = tid / 160;        // 0/1: which row of the stage-unit
    const float* xcol = x + ((n * 32 + kg_s * 8) * 16 + d) * HW + wq * 4;

    // compute coords: wave f = w-fifth (32 w); per wave 2 rows x 2 wtiles
    const int s16  = lane & 15;
    const int kg_r = lane >> 4;
    const int f    = tid >> 6;
    int rdoff[2][3];
    #pragma unroll
    for (int wt = 0; wt < 2; ++wt)
        #pragma unroll
        for (int kw = 0; kw < 3; ++kw)
            rdoff[wt][kw] = lds_half_idx(0, f * 32 + wt * 16 + s16 + kw, kg_r);
    float* obase = out + (n * 32 + s16) * DHW + d * HW + kg_r * 4 + f * 32;

    // weight fragments (L2-resident table from prep kernel)
    half8 wf0[9], wf1[9];
    {
        const half8* fb = reinterpret_cast<const half8*>(ws);
        #pragma unroll
        for (int t = 0; t < 9; ++t) {
            wf0[t] = fb[(t * 2 + 0) * 64 + lane];
            wf1[t] = fb[(t * 2 + 1) * 64 + lane];
        }
    }

    const floatx4 z4 = {0.f, 0.f, 0.f, 0.f};

    // ISSUE: loads for stage-unit k = input rows {h0+2k-1, h0+2k}.
    // Interior units (block-uniform test, k is a literal at every call site)
    // issue UNCONDITIONAL loads -> no cndmask -> no self-drain; results are
    // first consumed by PACK(k) several barriers later.
    auto ISSUE = [&](int k, SR& R) {
        const int h_in = h0 + 2 * k - 1 + rr;
        const float* p = xcol + h_in * 160;
        if (h0 + 2 * k - 1 >= 0 && h0 + 2 * k <= 159) {   // uniform branch
            #pragma unroll
            for (int c = 0; c < 8; ++c)
                R.v[c] = *reinterpret_cast<const floatx4*>(p + c * DHW);
        } else {                                          // edge chunks only
            const bool ok = (unsigned)h_in < 160u;
            #pragma unroll
            for (int c = 0; c < 8; ++c)
                R.v[c] = ok ? *reinterpret_cast<const floatx4*>(p + c * DHW) : z4;
        }
    };
    auto PACK = [&](int k, SR& R) {    // cvt + ds_write S_k into ring
        const int slot = (2 * k + rr) % 6;
        #pragma unroll
        for (int u = 0; u < 4; ++u) {
            half8 pk;
            #pragma unroll
            for (int c = 0; c < 8; ++c) pk[c] = (_Float16)R.v[c][u];
            *reinterpret_cast<half8*>(
                &ldsh[lds_half_idx(slot, wq * 4 + 1 + u, kg_s)]) = pk;
        }
        if (wq == 0) {
            half8 zz = {};
            *reinterpret_cast<half8*>(&ldsh[lds_half_idx(slot, 0, kg_s)]) = zz;
        }
        if (wq == 39) {
            half8 zz = {};
            *reinterpret_cast<half8*>(&ldsh[lds_half_idx(slot, 161, kg_s)]) = zz;
        }
    };
    auto COMPUTE = [&](int t) {        // output rows h0+2t, h0+2t+1
        #pragma unroll
        for (int row_l = 0; row_l < 2; ++row_l) {
            #pragma unroll
            for (int wt = 0; wt < 2; ++wt) {
                floatx4 a0 = {0.f, 0.f, 0.f, 0.f};
                floatx4 a1 = {0.f, 0.f, 0.f, 0.f};
                #pragma unroll
                for (int kh = 0; kh < 3; ++kh) {
                    const int slot = (2 * t + row_l + kh) % 6;
                    const int so   = slot * ROWB;
                    #pragma unroll
                    for (int kw = 0; kw < 3; ++kw) {
                        const half8 a = *reinterpret_cast<const half8*>(
                                &ldsh[so + rdoff[wt][kw]]);
                        const int tap = kh * 3 + kw;
                        a0 = __builtin_amdgcn_mfma_f32_16x16x32_f16(a, wf0[tap], a0, 0, 0, 0);
                        a1 = __builtin_amdgcn_mfma_f32_16x16x32_f16(a, wf1[tap], a1, 0, 0, 0);
                    }
                }
                float* op = obase + (h0 + 2 * t + row_l) * 160 + wt * 16;
                *reinterpret_cast<floatx4*>(op)            = a0;  // o 0..15
                *reinterpret_cast<floatx4*>(op + 16 * DHW) = a1;  // o 16..31
            }
        }
    };

    // ---------------- pipeline: 5 tiles, units k=0..5 ----------------------
    // Race safety: PACK(k) writes slots last READ by COMPUTE(k-3), which is
    // >=3 barriers earlier (verified in R6, same slot algebra).
    SR A, B;
    ISSUE(0, A);
    ISSUE(1, B);
    PACK(0, A);            // fresh slots; no barrier needed yet
    ISSUE(2, A);

    barrier_raw(); PACK(1, B); barrier_raw(); ISSUE(3, B); COMPUTE(0);
    barrier_raw(); PACK(2, A); barrier_raw(); ISSUE(4, A); COMPUTE(1);
    barrier_raw(); PACK(3, B); barrier_raw(); ISSUE(5, B); COMPUTE(2);
    barrier_raw(); PACK(4, A); barrier_raw();              COMPUTE(3);
    barrier_raw(); PACK(5, B); barrier_raw();              COMPUTE(4);
}

extern "C" void kernel_launch(void* const* d_in, const int* in_sizes, int n_in,
                              void* d_out, int out_size, void* d_ws, size_t ws_size,
                              hipStream_t stream) {
    const float* x = (const float*)d_in[0];
    const float* w = (const float*)d_in[1];
    float* out = (float*)d_out;
    _Float16* ws = (_Float16*)d_ws;     // 9216 halfs = 18 KB scratch
    bnn_wprep_kernel<<<dim3(1), dim3(256), 0, stream>>>(w, ws);
    // grid: 8 n * 16 d * 16 h-chunks of 10 rows
    bnn_conv3d_ring<<<dim3(2048), dim3(320), 0, stream>>>(x, ws, out);
}

// Round 9
// 324.399 us; speedup vs baseline: 1.4682x; 1.4682x over previous
//
#include <hip/hip_runtime.h>

// BNN conv3d forward: x (8,32,16,160,160) f32, w (32,32,1,3,3) f32
// out[n,o,d,h,w] = sum_i sum_{kh,kw} x[n,i,d,h+kh-1,w+kw-1] * we[o,i,kh,kw]
// we = (mean|w| over taps) * sign(w).  Implicit GEMM, mfma_f32_16x16x32_f16.
//
// Round-9: R5 geometry EXACTLY (TH=4 full-row tile, 62KB LDS, 512 thr,
// traffic-exact), pipelined over the d dimension: block walks 4 independent
// d-slices; loads for slice k+1 are issued UNCONDITIONALLY (clamped address,
// zeros applied at pack time -> no cndmask self-drain) and stay in flight
// across raw lgkm-only barriers while slice k computes. Waves specialize in
// o (wave = row x o-half): wf 72->36 regs to fit 64 in-flight load regs
// under the 128-VGPR / 2-blocks-per-CU budget.

typedef _Float16 half8 __attribute__((ext_vector_type(8)));
typedef float    floatx4 __attribute__((ext_vector_type(4)));

#define DHW  409600   // 16*160*160 (channel stride)
#define HW   25600    // 160*160   (d stride)
#define ROWB (162*32) // halfs per LDS row

__device__ __forceinline__ int swz(int w1, int kg) {
    // round-5-verified swizzle: 64B-cell swap + 16B sub-block XOR
    const int w1x = w1 ^ ((w1 >> 2) & 1);
    const int skg = kg ^ (((w1 >> 1) ^ (w1 >> 3)) & 3);
    return w1x * 32 + skg * 8;
}

__device__ __forceinline__ void barrier_raw() {
    // LDS-visibility barrier that does NOT drain vmcnt (loads stay in flight)
    __builtin_amdgcn_sched_barrier(0);
    asm volatile("s_waitcnt lgkmcnt(0)" ::: "memory");
    __builtin_amdgcn_s_barrier();
    __builtin_amdgcn_sched_barrier(0);
}

// ---- kernel 1: effective-weight fragments -> ws (18 KB) -------------------
// ws[((t*2+p)*64 + l)*8 + j] = we[o=p*16+(l&15)][i=(l>>4)*8+j][t]
__global__ void bnn_wprep_kernel(const float* __restrict__ w,
                                 _Float16* __restrict__ ws) {
    const int tid = threadIdx.x;
    #pragma unroll
    for (int p4 = 0; p4 < 4; ++p4) {
        const int oi = tid * 4 + p4;
        const int o  = oi >> 5;
        const int i  = oi & 31;
        const float* wp = w + oi * 9;
        float s = 0.f;
        #pragma unroll
        for (int t = 0; t < 9; ++t) s += fabsf(wp[t]);
        s *= (1.f / 9.f);
        const int l = ((i >> 3) << 4) | (o & 15);
        const int p = o >> 4;
        const int j = i & 7;
        #pragma unroll
        for (int t = 0; t < 9; ++t) {
            const float v  = wp[t];
            const float sg = (v > 0.f) ? 1.f : ((v < 0.f) ? -1.f : 0.f);
            ws[((t * 2 + p) * 64 + l) * 8 + j] = (_Float16)(s * sg);
        }
    }
}

// ---- kernel 2: the conv ---------------------------------------------------
__global__ __launch_bounds__(512, 4) void bnn_conv3d_pipe(
        const float* __restrict__ x, const _Float16* __restrict__ ws,
        float* __restrict__ out) {
    __shared__ __align__(16) _Float16 ldsh[6 * ROWB];   // 62208 B

    const int tid  = threadIdx.x;
    const int lane = tid & 63;
    const int wid  = tid >> 6;

    // grid 1280 = 8n * 40ht * 4dq; block walks d = dq*4 + k, k = 0..3
    const int bid = blockIdx.x;
    const int dq  = bid & 3;
    const int ht  = (bid >> 2) % 40;
    const int n   = bid / 160;
    const int h0  = ht * 4;
    const int d0  = dq * 4;

    // ---- staging coords: item = (r:6, kg:4, wq:40) = 960, 2/thread --------
    const int  wq0 = tid % 40, kg0 = (tid / 40) & 3, r0 = tid / 160;
    const int  id1 = tid + 512;
    const int  wq1 = id1 % 40, kg1 = (id1 / 40) & 3, r1 = id1 / 160;
    const bool act1 = tid < 448;           // wave-uniform (waves 0..6)
    const int  hi0 = h0 - 1 + r0,  hi1 = h0 - 1 + r1;
    const bool ok0 = (unsigned)hi0 < 160u, ok1 = (unsigned)hi1 < 160u;
    const int  hc0 = ok0 ? hi0 : (hi0 < 0 ? 0 : 159);   // clamped addr row
    const int  hc1 = ok1 ? hi1 : (hi1 < 0 ? 0 : 159);
    const float* xb0 = x + (n * 32 + kg0 * 8) * DHW + hc0 * 160 + wq0 * 4;
    const float* xb1 = x + (n * 32 + kg1 * 8) * DHW + hc1 * 160 + wq1 * 4;

    // ---- compute coords: wave = (row = wid&3, o-half = wid>>2) ------------
    const int s16  = lane & 15;
    const int kg_r = lane >> 4;
    const int row  = wid & 3;
    const int oh   = wid >> 2;

    floatx4 A[8], B[8];

    // ISSUE: unconditional float4 loads (clamped addr; zeroing happens at
    // PACK on the converted value, AFTER the mandatory vmcnt wait).
    auto ISSUE = [&](int d, floatx4* R0, floatx4* R1) {
        const float* p0 = xb0 + d * HW;
        #pragma unroll
        for (int c = 0; c < 8; ++c)
            R0[c] = *reinterpret_cast<const floatx4*>(p0 + c * DHW);
        if (act1) {
            const float* p1 = xb1 + d * HW;
            #pragma unroll
            for (int c = 0; c < 8; ++c)
                R1[c] = *reinterpret_cast<const floatx4*>(p1 + c * DHW);
        }
    };
    auto PACK = [&](floatx4* R0, floatx4* R1) {
        #pragma unroll
        for (int u = 0; u < 4; ++u) {
            half8 pk;
            #pragma unroll
            for (int c = 0; c < 8; ++c)
                pk[c] = ok0 ? (_Float16)R0[c][u] : (_Float16)0.f;
            *reinterpret_cast<half8*>(
                &ldsh[r0 * ROWB + swz(wq0 * 4 + 1 + u, kg0)]) = pk;
        }
        if (act1) {
            #pragma unroll
            for (int u = 0; u < 4; ++u) {
                half8 pk;
                #pragma unroll
                for (int c = 0; c < 8; ++c)
                    pk[c] = ok1 ? (_Float16)R1[c][u] : (_Float16)0.f;
                *reinterpret_cast<half8*>(
                    &ldsh[r1 * ROWB + swz(wq1 * 4 + 1 + u, kg1)]) = pk;
            }
        }
    };

    // weight fragments: this wave's o-half only (36 VGPR)
    half8 wf[9];

    auto COMPUTE = [&](int d) {
        float* ob = out + (n * 32 + oh * 16 + s16) * DHW + d * HW
                        + (h0 + row) * 160 + kg_r * 4;
        #pragma unroll
        for (int gp = 0; gp < 5; ++gp) {
            const int ga = gp * 2, gb = gp * 2 + 1;
            floatx4 aa = {0.f, 0.f, 0.f, 0.f};
            floatx4 ab = {0.f, 0.f, 0.f, 0.f};
            #pragma unroll
            for (int kh = 0; kh < 3; ++kh) {
                const int rb = (row + kh) * ROWB;
                #pragma unroll
                for (int kw = 0; kw < 3; ++kw) {
                    const half8 fa = *reinterpret_cast<const half8*>(
                            &ldsh[rb + swz(ga * 16 + s16 + kw, kg_r)]);
                    const half8 fb = *reinterpret_cast<const half8*>(
                            &ldsh[rb + swz(gb * 16 + s16 + kw, kg_r)]);
                    const int t = kh * 3 + kw;
                    aa = __builtin_amdgcn_mfma_f32_16x16x32_f16(fa, wf[t], aa, 0, 0, 0);
                    ab = __builtin_amdgcn_mfma_f32_16x16x32_f16(fb, wf[t], ab, 0, 0, 0);
                }
            }
            *reinterpret_cast<floatx4*>(ob + ga * 16) = aa;
            *reinterpret_cast<floatx4*>(ob + gb * 16) = ab;
        }
    };

    // ---- halo columns w1 in {0,161}: zero ONCE (never overwritten) --------
    if (tid < 192) {
        const int pos = tid >> 4, word = tid & 15;
        const int r   = pos >> 1;
        const int w1  = (pos & 1) ? 161 : 0;   // both map to themselves in swz
        reinterpret_cast<unsigned int*>(ldsh)[(r * 162 + w1) * 16 + word] = 0u;
    }

    // ---------------- pipeline over 4 d-slices -----------------------------
    // vmcnt ordering: L(k+1) is always the youngest VMEM when wf/fl(k) are
    // consumed, so no compiler-inserted wait can drain it.
    ISSUE(d0 + 0, A, B);               // L0 (oldest)
    {
        const half8* fbp = reinterpret_cast<const half8*>(ws);
        #pragma unroll
        for (int t = 0; t < 9; ++t)
            wf[t] = fbp[(t * 2 + oh) * 64 + lane];
    }
    __builtin_amdgcn_sched_barrier(0); // pin: wf issued before P0's waits
    PACK(A, B);                        // waits L0 (wf stays in flight)
    ISSUE(d0 + 1, A, B);               // L1
    barrier_raw();
    COMPUTE(d0 + 0);                   // L1 in flight throughout
    barrier_raw();
    PACK(A, B);
    ISSUE(d0 + 2, A, B);               // L2
    barrier_raw();
    COMPUTE(d0 + 1);
    barrier_raw();
    PACK(A, B);
    ISSUE(d0 + 3, A, B);               // L3
    barrier_raw();
    COMPUTE(d0 + 2);
    barrier_raw();
    PACK(A, B);
    barrier_raw();
    COMPUTE(d0 + 3);
}

extern "C" void kernel_launch(void* const* d_in, const int* in_sizes, int n_in,
                              void* d_out, int out_size, void* d_ws, size_t ws_size,
                              hipStream_t stream) {
    const float* x = (const float*)d_in[0];
    const float* w = (const float*)d_in[1];
    float* out = (float*)d_out;
    _Float16* ws = (_Float16*)d_ws;     // 9216 halfs = 18 KB scratch
    bnn_wprep_kernel<<<dim3(1), dim3(256), 0, stream>>>(w, ws);
    // grid: 8 n * 40 h-tiles * 4 d-quads (block walks 4 d-slices)
    bnn_conv3d_pipe<<<dim3(1280), dim3(512), 0, stream>>>(x, ws, out);
}